// Round 28
// baseline (113.889 us; speedup 1.0000x reference)
//
#include <hip/hip_runtime.h>

#define B_ 4
#define S_ 2048
#define D_ 768
#define H_ 12
#define HD_ 64
#define T_ (B_ * S_)  // 8192

typedef __bf16 bf16x8 __attribute__((ext_vector_type(8)));
typedef __bf16 bf16x4 __attribute__((ext_vector_type(4)));
typedef float  f32x4  __attribute__((ext_vector_type(4)));

__device__ __forceinline__ f32x4 mfma16(bf16x8 a, bf16x8 b, f32x4 c) {
  return __builtin_amdgcn_mfma_f32_16x16x32_bf16(a, b, c, 0, 0, 0);
}

// 2^x via v_exp_f32 (scores are pre-scaled by log2e at weight-convert time)
__device__ __forceinline__ float fexp2(float x) {
  float r;
  asm("v_exp_f32 %0, %1" : "=v"(r) : "v"(x));
  return r;
}

// async global->LDS, 16B per lane. LDS dest is wave-uniform base + lane*16.
__device__ __forceinline__ void gload16(const __bf16* g, __bf16* lds) {
  __builtin_amdgcn_global_load_lds(
      (__attribute__((address_space(1))) void*)g,
      (__attribute__((address_space(3))) void*)lds, 16, 0, 0);
}

// ---------------- fused fp32 -> bf16 convert (x + 4 weights, 1 launch) -------
__global__ void cvt_all(const float* __restrict__ x,
                        const float* __restrict__ wq,
                        const float* __restrict__ wk,
                        const float* __restrict__ wv,
                        const float* __restrict__ wo,
                        __bf16* __restrict__ out) {
  constexpr int XN4 = T_ * D_ / 4;
  constexpr int WN4 = D_ * D_ / 4;
  const int i = blockIdx.x * blockDim.x + threadIdx.x;
  if (i >= XN4 + 4 * WN4) return;
  const float* src;
  int k;
  float scale = 1.0f;
  if (i < XN4) {
    src = x;
    k = i;
  } else {
    const int j = i - XN4;
    const int wsel = j / WN4;
    k = j - wsel * WN4;
    src = (wsel == 0) ? wq : (wsel == 1) ? wk : (wsel == 2) ? wv : wo;
    if (wsel == 1) scale = 0.18033688f;  // 0.125 * log2(e)
  }
  const float4 v = reinterpret_cast<const float4*>(src)[k];
  bf16x4 o;
  o[0] = (__bf16)(v.x * scale);
  o[1] = (__bf16)(v.y * scale);
  o[2] = (__bf16)(v.z * scale);
  o[3] = (__bf16)(v.w * scale);
  reinterpret_cast<bf16x4*>(out)[i] = o;
}

// ---------------- GEMM: C[m][n] = sum_k A[m][k] * W[n][k]  (B^T layout) ------
// r26/r27-exact: 128x128, BK=64, A dbuf + B single-buffer (48 KB LDS,
// 3 blk/CU), counted vmcnt, swizzled LDS, XCD-slab remap, two-pass
// LDS-transpose epilogue + direct vectorized V^T store.
template <int MODE>
__global__ __launch_bounds__(256)
__attribute__((amdgpu_waves_per_eu(3)))
void gemm_bt(const __bf16* __restrict__ A,
             const __bf16* __restrict__ W0, const __bf16* __restrict__ W1,
             const __bf16* __restrict__ W2,
             __bf16* __restrict__ Oq, __bf16* __restrict__ Ok,
             __bf16* __restrict__ Ov,
             float* __restrict__ fout, const float* __restrict__ bias) {
  constexpr int K = D_;       // 768
  constexpr int NT = K / 64;  // 12 K-tiles
  __shared__ __align__(16) char smem[49152];  // sA dbuf 32K | sB single 16K
  __bf16* sA0 = reinterpret_cast<__bf16*>(smem);          // [2][128*64]
  __bf16* sB0 = reinterpret_cast<__bf16*>(smem + 32768);  // [128*64]

  const int tid = threadIdx.x;
  const int l = tid & 63;
  const int w = tid >> 6;

  const int flat = blockIdx.y * 64 + blockIdx.x;
  const int xcd = flat & 7;
  const int q = flat >> 3;
  const int mtile = xcd * 8 + (q & 7);
  const int pan = q >> 3;
  const int m0 = mtile * 128;

  int mat, n0;
  const __bf16* Wm;
  if (MODE == 0) {
    mat = pan / 6;
    n0 = (pan % 6) * 128;
    Wm = (mat == 0) ? W0 : (mat == 1) ? W1 : W2;
  } else {
    mat = 0;
    n0 = pan * 128;
    Wm = W0;
  }

  const int srow = l >> 3;                // 0..7
  const int scol = ((l & 7) ^ srow) * 8;  // source col (elements)
  const __bf16* gA[4];
  const __bf16* gB[4];
#pragma unroll
  for (int i = 0; i < 4; ++i) {
    const int c = w * 4 + i;
    gA[i] = A + (size_t)(m0 + c * 8 + srow) * K + scol;
    gB[i] = Wm + (size_t)(n0 + c * 8 + srow) * K + scol;
  }

  f32x4 acc[4][4] = {};
  const int wr = w >> 1, wc = w & 1;
  const int fr = l & 15, fq = l >> 4;
  const int swz = (fr & 7) << 4;

  // prologue (FIFO): A(0) x4, B(0) x4, A(1) x4  -> 12 in flight
#pragma unroll
  for (int i = 0; i < 4; ++i) gload16(gA[i], &sA0[(w * 4 + i) * 512]);
#pragma unroll
  for (int i = 0; i < 4; ++i) gload16(gB[i], &sB0[(w * 4 + i) * 512]);
#pragma unroll
  for (int i = 0; i < 4; ++i)
    gload16(gA[i] + 64, &sA0[8192 + (w * 4 + i) * 512]);

  int cur = 0;
  for (int kt = 0; kt < NT; ++kt) {
    if (kt + 1 < NT)
      asm volatile("s_waitcnt vmcnt(4)" ::: "memory");
    else
      asm volatile("s_waitcnt vmcnt(0)" ::: "memory");
    __builtin_amdgcn_s_barrier();

    const char* ab = reinterpret_cast<const char*>(&sA0[cur * 8192]);
    const char* bb = reinterpret_cast<const char*>(sB0);
#pragma unroll
    for (int ks = 0; ks < 2; ++ks) {
      bf16x8 af[4], bfr[4];
#pragma unroll
      for (int mi = 0; mi < 4; ++mi)
        af[mi] = *reinterpret_cast<const bf16x8*>(
            ab + (wr * 64 + mi * 16 + fr) * 128 +
            ((ks * 64 + fq * 16) ^ swz));
#pragma unroll
      for (int ni = 0; ni < 4; ++ni)
        bfr[ni] = *reinterpret_cast<const bf16x8*>(
            bb + (wc * 64 + ni * 16 + fr) * 128 +
            ((ks * 64 + fq * 16) ^ swz));
#pragma unroll
      for (int mi = 0; mi < 4; ++mi)
#pragma unroll
        for (int ni = 0; ni < 4; ++ni)
          acc[mi][ni] = mfma16(af[mi], bfr[ni], acc[mi][ni]);
    }
    __builtin_amdgcn_s_barrier();  // all warps done reading sA[cur] + sB

    if (kt + 1 < NT) {
      const int ko = (kt + 1) * 64;
#pragma unroll
      for (int i = 0; i < 4; ++i)
        gload16(gB[i] + ko, &sB0[(w * 4 + i) * 512]);
    }
    if (kt + 2 < NT) {
      const int ko = (kt + 2) * 64;
#pragma unroll
      for (int i = 0; i < 4; ++i)
        gload16(gA[i] + ko, &sA0[cur * 8192 + (w * 4 + i) * 512]);
    }
    cur ^= 1;
  }

  // ---------------- epilogue ----------------
  if (MODE == 0 && mat == 2) {
#pragma unroll
    for (int mi = 0; mi < 4; ++mi) {
      const int mbase = m0 + wr * 64 + mi * 16 + fq * 4;
      const int b = mbase >> 11, s = mbase & (S_ - 1);
#pragma unroll
      for (int ni = 0; ni < 4; ++ni) {
        const int o = n0 + wc * 64 + ni * 16 + fr;
        const int h = o >> 6, hd = o & 63;
        bf16x4 vv;
#pragma unroll
        for (int r = 0; r < 4; ++r) vv[r] = (__bf16)acc[mi][ni][r];
        *reinterpret_cast<bf16x4*>(
            &Ov[((size_t)((b * H_ + h) * HD_ + hd)) * S_ + s]) = vv;
      }
    }
  } else {
    float* fW = reinterpret_cast<float*>(smem) + w * 2048;
#pragma unroll
    for (int half = 0; half < 2; ++half) {
#pragma unroll
      for (int mi2 = 0; mi2 < 2; ++mi2)
#pragma unroll
        for (int ni = 0; ni < 4; ++ni)
#pragma unroll
          for (int r = 0; r < 4; ++r)
            fW[(mi2 * 16 + fq * 4 + r) * 64 + ni * 16 + fr] =
                acc[half * 2 + mi2][ni][r];
      if (MODE == 1) {
        const int ocol = n0 + wc * 64 + fr * 4;
        const float4 bs = *reinterpret_cast<const float4*>(&bias[ocol]);
#pragma unroll
        for (int it = 0; it < 8; ++it) {
          const int lrow = it * 4 + fq;
          f32x4 v = *reinterpret_cast<const f32x4*>(&fW[lrow * 64 + fr * 4]);
          v[0] += bs.x;
          v[1] += bs.y;
          v[2] += bs.z;
          v[3] += bs.w;
          *reinterpret_cast<f32x4*>(
              &fout[(size_t)(m0 + wr * 64 + half * 32 + lrow) * D_ + ocol]) =
              v;
        }
      } else {
        const int o = n0 + wc * 64;  // 64-aligned -> h const
        const int h = o >> 6;
        __bf16* dst = (mat == 0) ? Oq : Ok;
#pragma unroll
        for (int it = 0; it < 8; ++it) {
          const int lrow = it * 4 + fq;
          const int m = m0 + wr * 64 + half * 32 + lrow;
          const int b = m >> 11, s = m & (S_ - 1);
          const f32x4 v =
              *reinterpret_cast<const f32x4*>(&fW[lrow * 64 + fr * 4]);
          bf16x4 ov;
#pragma unroll
          for (int r = 0; r < 4; ++r) ov[r] = (__bf16)v[r];
          *reinterpret_cast<bf16x4*>(
              &dst[((size_t)((b * H_ + h) * S_ + s)) * HD_ + fr * 4]) = ov;
        }
      }
    }
  }
}

// ---------------- causal flash attention: 8-warp 128-q blocks -----------------
// r28: attn was FILL-dominated (405 MB staged, floor ~39 us vs issue ~15 us).
// 128 q-rows/block (8 warps x 16 rows) halves staged bytes (209 MB, floor
// ~20 us) while keeping the slimmed r27 per-warp inner loop IDENTICAL.
// Grid 768 = 3 blocks/CU x 8 warps = 24 waves/CU resident. r17's balanced
// triple schedule (verified correct there) equalizes per-CU causal work
// (now in its regime: 3 co-resident blocks, no backfill). Per warp stages
// 1 K-chunk + 1 V-chunk; counted vmcnt: prologue K0,V0,K1 -> top vmcnt(1)
// (K(t)+V(t) landed, K(t+1) in flight); post-barrier issue V(t+1), K(t+2).
// nt = 2*qtile+2 >= 2 (no nt=1 edge). V single-buffered (r25), vote-first
// defer-max (r27), deferred l-reduction (r25).
__global__ __launch_bounds__(512)
__attribute__((amdgpu_waves_per_eu(6)))
void attn_kernel(const __bf16* __restrict__ Q, const __bf16* __restrict__ Kt,
                 const __bf16* __restrict__ Vt, __bf16* __restrict__ C) {
  __shared__ __align__(16) __bf16 sK[2][64 * 64];  // 16 KB, swizzled, dbuf
  __shared__ __align__(16) __bf16 sV[64 * 64];     // 8 KB, single buf
  __shared__ __align__(16) __bf16 sP[8][16 * 64];  // 16 KB, per-warp P

  const int tid = threadIdx.x;
  const int l = tid & 63;
  const int w = tid >> 6;  // 0..7
  const int fr = l & 15, fq = l >> 4;
  const int bx = blockIdx.x;
  const int xcd = bx & 7;
  const int j = bx >> 3;  // [0, 96)
  // balanced triple schedule (r17): CU hosts layers L=0,1,2; per-CU qtile
  // triples sum 22/23. L0 deep-first.
  const int L = j >> 5;
  const int u = j & 31;
  const int i = u & 15;
  const int rep = u >> 4;
  int qtile;
  if (L == 0) qtile = 15 - i;
  else if (L == 1) qtile = (i < 8) ? 2 * i : 2 * i - 15;
  else qtile = (i < 8) ? 7 - i : 23 - i;
  const int bh = xcd + 8 * (2 * L + rep);  // head in [0,48), 6 per XCD
  const int qb = qtile * 128;
  const int qbw = qb + w * 16;  // this warp's 16 q-rows

  const __bf16* qh = Q + (size_t)bh * S_ * HD_;
  const __bf16* kh = Kt + (size_t)bh * S_ * HD_;
  const __bf16* vh = Vt + (size_t)bh * HD_ * S_;
  char* sPb = reinterpret_cast<char*>(&sP[w][0]);

  const int srow = l >> 3;                       // 0..7
  const int scol = ((l & 7) * 8) ^ (srow << 3);  // pre-swizzled source col
  const int swz = (fr & 7) << 4;                 // read-side XOR (bytes)

  bf16x8 qf[2];
#pragma unroll
  for (int ks = 0; ks < 2; ++ks)
    qf[ks] = *reinterpret_cast<const bf16x8*>(
        &qh[(size_t)(qbw + fr) * HD_ + ks * 32 + fq * 8]);

  f32x4 acc[4] = {};
  float mrow = -1e30f, lrow = 0.f;  // lrow: per-lane PARTIAL sum (deferred)

  const int nt = 2 * qtile + 2;  // kv tiles 0 .. (qb+128)/64 - 1; >= 2
  int cur = 0;

  // prologue (FIFO): K0, V0, K1  (1 load each per warp; 3 in flight)
  gload16(kh + (size_t)(w * 8 + srow) * HD_ + scol, &sK[0][w * 512]);
  gload16(vh + (size_t)(w * 8 + srow) * S_ + scol, &sV[w * 512]);
  gload16(kh + (size_t)(64 + w * 8 + srow) * HD_ + scol, &sK[1][w * 512]);

  for (int t = 0; t < nt; ++t) {
    // complete all but the newest 1 (= K(t+1)); K(t)+V(t) landed
    if (t + 1 < nt)
      asm volatile("s_waitcnt vmcnt(1)" ::: "memory");
    else
      asm volatile("s_waitcnt vmcnt(0)" ::: "memory");
    __builtin_amdgcn_s_barrier();  // all warps' stage(t) landed

    const int kv0 = t * 64;
    if (kv0 <= qbw + 15) {
      const char* kb = reinterpret_cast<const char*>(&sK[cur][0]);
      const char* vb = reinterpret_cast<const char*>(&sV[0]);

      f32x4 s[4];
      __builtin_amdgcn_s_setprio(1);
#pragma unroll
      for (int c = 0; c < 4; ++c) {
        const int row = c * 16 + fr;
        bf16x8 kf0 = *reinterpret_cast<const bf16x8*>(
            kb + row * 128 + ((fq * 16) ^ swz));
        bf16x8 kf1 = *reinterpret_cast<const bf16x8*>(
            kb + row * 128 + ((fq * 16 + 64) ^ swz));
        f32x4 z = {};
        z = mfma16(kf0, qf[0], z);
        z = mfma16(kf1, qf[1], z);
        s[c] = z;
      }
      __builtin_amdgcn_s_setprio(0);

      if (kv0 + 63 > qbw) {
        const int qi = qbw + fr;
#pragma unroll
        for (int c = 0; c < 4; ++c)
#pragma unroll
          for (int r = 0; r < 4; ++r) {
            const int kvi = kv0 + c * 16 + fq * 4 + r;
            if (kvi > qi) s[c][r] = -1e30f;
          }
      }

      // lane-local max tree; vote-first defer (no shfl on common path)
      float tml = -1e30f;
#pragma unroll
      for (int c = 0; c < 4; ++c)
#pragma unroll
        for (int r = 0; r < 4; ++r) tml = fmaxf(tml, s[c][r]);
      const bool defer = __all(tml - mrow <= 8.0f);
      float mn;
      if (defer) {
        mn = mrow;
      } else {
        float tm = fmaxf(tml, __shfl_xor(tml, 16));
        tm = fmaxf(tm, __shfl_xor(tm, 32));
        mn = fmaxf(mrow, tm);
        const float fac = fexp2(mrow - mn);  // uniform across fq of a q-row
        mrow = mn;
        lrow *= fac;  // valid on per-lane partial sums
#pragma unroll
        for (int dt = 0; dt < 4; ++dt)
#pragma unroll
          for (int r = 0; r < 4; ++r) acc[dt][r] *= fac;
      }
      float sum = 0.f;
#pragma unroll
      for (int c = 0; c < 4; ++c) {
        bf16x4 pc;
#pragma unroll
        for (int r = 0; r < 4; ++r) {
          const float p = fexp2(s[c][r] - mn);
          sum += p;
          pc[r] = (__bf16)p;
        }
        const int bo = (c * 32 + fq * 8) ^ swz;
        *reinterpret_cast<bf16x4*>(sPb + fr * 128 + bo) = pc;
      }
      lrow += sum;  // cross-lane reduction deferred to epilogue

      bf16x8 pa[2];
#pragma unroll
      for (int ks = 0; ks < 2; ++ks) {
        const int bo = (ks * 64 + fq * 16) ^ swz;
        pa[ks] = *reinterpret_cast<const bf16x8*>(sPb + fr * 128 + bo);
      }

      __builtin_amdgcn_s_setprio(1);
#pragma unroll
      for (int dt = 0; dt < 4; ++dt) {
        const int row = dt * 16 + fr;
        bf16x8 vf0 = *reinterpret_cast<const bf16x8*>(
            vb + row * 128 + ((fq * 16) ^ swz));
        bf16x8 vf1 = *reinterpret_cast<const bf16x8*>(
            vb + row * 128 + ((fq * 16 + 64) ^ swz));
        acc[dt] = mfma16(vf0, pa[0], acc[dt]);
        acc[dt] = mfma16(vf1, pa[1], acc[dt]);
      }
      __builtin_amdgcn_s_setprio(0);
    }

    __builtin_amdgcn_s_barrier();  // all warps done reading sK[cur] + sV

    // stage V(t+1) FIRST (must land by next iter; sV reads ended above),
    // then K(t+2) (stays in flight one extra iter)
    if (t + 1 < nt) {
      const int kvn = (t + 1) * 64;
      gload16(vh + (size_t)(w * 8 + srow) * S_ + kvn + scol, &sV[w * 512]);
    }
    if (t + 2 < nt) {
      const int kvn = (t + 2) * 64;
      gload16(kh + (size_t)(kvn + w * 8 + srow) * HD_ + scol,
              &sK[cur][w * 512]);
    }
    cur ^= 1;
  }

  // epilogue: finish the deferred l reduction, then lane-local store
  float lt = lrow;
  lt += __shfl_xor(lt, 16);
  lt += __shfl_xor(lt, 32);
  const int b = bh / H_, h = bh % H_;
  const float inv_l = 1.0f / lt;
  const int qrow = qbw + fr;
#pragma unroll
  for (int dt = 0; dt < 4; ++dt) {
    bf16x4 ov;
#pragma unroll
    for (int r = 0; r < 4; ++r) ov[r] = (__bf16)(acc[dt][r] * inv_l);
    *reinterpret_cast<bf16x4*>(
        &C[((size_t)(b * S_ + qrow)) * D_ + h * HD_ + dt * 16 + fq * 4]) = ov;
  }
}

// ---------------- workspace layout (bf16 elements) ---------------------------
static constexpr size_t XB_OFF = 0;
static constexpr size_t WQ_OFF = XB_OFF + (size_t)T_ * D_;
static constexpr size_t WK_OFF = WQ_OFF + (size_t)D_ * D_;
static constexpr size_t WV_OFF = WK_OFF + (size_t)D_ * D_;
static constexpr size_t WO_OFF = WV_OFF + (size_t)D_ * D_;
static constexpr size_t Q_OFF = WO_OFF + (size_t)D_ * D_;
static constexpr size_t K_OFF = Q_OFF + (size_t)T_ * D_;
static constexpr size_t V_OFF = K_OFF + (size_t)T_ * D_;
static constexpr size_t C_OFF = V_OFF + (size_t)T_ * D_;

extern "C" void kernel_launch(void* const* d_in, const int* in_sizes, int n_in,
                              void* d_out, int out_size, void* d_ws,
                              size_t ws_size, hipStream_t stream) {
  const float* x = (const float*)d_in[0];
  const float* wq = (const float*)d_in[1];
  const float* wk = (const float*)d_in[2];
  const float* wv = (const float*)d_in[3];
  const float* wo = (const float*)d_in[4];
  const float* bo = (const float*)d_in[5];
  float* out = (float*)d_out;
  __bf16* ws = (__bf16*)d_ws;

  __bf16* xb = ws + XB_OFF;
  __bf16* wqb = ws + WQ_OFF;
  __bf16* wkb = ws + WK_OFF;
  __bf16* wvb = ws + WV_OFF;
  __bf16* wob = ws + WO_OFF;
  __bf16* qbuf = ws + Q_OFF;
  __bf16* kbuf = ws + K_OFF;
  __bf16* vbuf = ws + V_OFF;
  __bf16* cbuf = ws + C_OFF;

  {
    constexpr int n4 = T_ * D_ / 4 + 4 * (D_ * D_ / 4);
    cvt_all<<<(n4 + 255) / 256, 256, 0, stream>>>(x, wq, wk, wv, wo, ws);
  }

  gemm_bt<0><<<dim3(64, 18), 256, 0, stream>>>(
      xb, wqb, wkb, wvb, qbuf, kbuf, vbuf, nullptr, nullptr);

  attn_kernel<<<dim3(768), 512, 0, stream>>>(qbuf, kbuf, vbuf, cbuf);

  gemm_bt<1><<<dim3(64, 6), 256, 0, stream>>>(
      cbuf, wob, nullptr, nullptr, nullptr, nullptr, nullptr, out, bo);
}

// Round 29
// 111.421 us; speedup vs baseline: 1.0222x; 1.0222x over previous
//
#include <hip/hip_runtime.h>

#define B_ 4
#define S_ 2048
#define D_ 768
#define H_ 12
#define HD_ 64
#define T_ (B_ * S_)  // 8192

typedef __bf16 bf16x8 __attribute__((ext_vector_type(8)));
typedef __bf16 bf16x4 __attribute__((ext_vector_type(4)));
typedef float  f32x4  __attribute__((ext_vector_type(4)));

__device__ __forceinline__ f32x4 mfma16(bf16x8 a, bf16x8 b, f32x4 c) {
  return __builtin_amdgcn_mfma_f32_16x16x32_bf16(a, b, c, 0, 0, 0);
}

// 2^x via v_exp_f32 (scores are pre-scaled by log2e at weight-convert time)
__device__ __forceinline__ float fexp2(float x) {
  float r;
  asm("v_exp_f32 %0, %1" : "=v"(r) : "v"(x));
  return r;
}

// async global->LDS, 16B per lane. LDS dest is wave-uniform base + lane*16.
__device__ __forceinline__ void gload16(const __bf16* g, __bf16* lds) {
  __builtin_amdgcn_global_load_lds(
      (__attribute__((address_space(1))) void*)g,
      (__attribute__((address_space(3))) void*)lds, 16, 0, 0);
}

// ---------------- fused fp32 -> bf16 convert (x + 4 weights, 1 launch) -------
__global__ void cvt_all(const float* __restrict__ x,
                        const float* __restrict__ wq,
                        const float* __restrict__ wk,
                        const float* __restrict__ wv,
                        const float* __restrict__ wo,
                        __bf16* __restrict__ out) {
  constexpr int XN4 = T_ * D_ / 4;
  constexpr int WN4 = D_ * D_ / 4;
  const int i = blockIdx.x * blockDim.x + threadIdx.x;
  if (i >= XN4 + 4 * WN4) return;
  const float* src;
  int k;
  float scale = 1.0f;
  if (i < XN4) {
    src = x;
    k = i;
  } else {
    const int j = i - XN4;
    const int wsel = j / WN4;
    k = j - wsel * WN4;
    src = (wsel == 0) ? wq : (wsel == 1) ? wk : (wsel == 2) ? wv : wo;
    if (wsel == 1) scale = 0.18033688f;  // 0.125 * log2(e)
  }
  const float4 v = reinterpret_cast<const float4*>(src)[k];
  bf16x4 o;
  o[0] = (__bf16)(v.x * scale);
  o[1] = (__bf16)(v.y * scale);
  o[2] = (__bf16)(v.z * scale);
  o[3] = (__bf16)(v.w * scale);
  reinterpret_cast<bf16x4*>(out)[i] = o;
}

// ---------------- GEMM: C[m][n] = sum_k A[m][k] * W[n][k]  (B^T layout) ------
// r26-exact: 128x128, BK=64, A dbuf + B single-buffer (48 KB LDS, 3 blk/CU),
// counted vmcnt (top vmcnt(4): A(t)+B(t) landed, A(t+1) in flight; post-
// barrier issue B(t+1) then A(t+2)), swizzled LDS, XCD-slab remap, two-pass
// LDS-transpose epilogue + direct vectorized V^T store.
template <int MODE>
__global__ __launch_bounds__(256)
__attribute__((amdgpu_waves_per_eu(3)))
void gemm_bt(const __bf16* __restrict__ A,
             const __bf16* __restrict__ W0, const __bf16* __restrict__ W1,
             const __bf16* __restrict__ W2,
             __bf16* __restrict__ Oq, __bf16* __restrict__ Ok,
             __bf16* __restrict__ Ov,
             float* __restrict__ fout, const float* __restrict__ bias) {
  constexpr int K = D_;       // 768
  constexpr int NT = K / 64;  // 12 K-tiles
  __shared__ __align__(16) char smem[49152];  // sA dbuf 32K | sB single 16K
  __bf16* sA0 = reinterpret_cast<__bf16*>(smem);          // [2][128*64]
  __bf16* sB0 = reinterpret_cast<__bf16*>(smem + 32768);  // [128*64]

  const int tid = threadIdx.x;
  const int l = tid & 63;
  const int w = tid >> 6;

  const int flat = blockIdx.y * 64 + blockIdx.x;
  const int xcd = flat & 7;
  const int q = flat >> 3;
  const int mtile = xcd * 8 + (q & 7);
  const int pan = q >> 3;
  const int m0 = mtile * 128;

  int mat, n0;
  const __bf16* Wm;
  if (MODE == 0) {
    mat = pan / 6;
    n0 = (pan % 6) * 128;
    Wm = (mat == 0) ? W0 : (mat == 1) ? W1 : W2;
  } else {
    mat = 0;
    n0 = pan * 128;
    Wm = W0;
  }

  const int srow = l >> 3;                // 0..7
  const int scol = ((l & 7) ^ srow) * 8;  // source col (elements)
  const __bf16* gA[4];
  const __bf16* gB[4];
#pragma unroll
  for (int i = 0; i < 4; ++i) {
    const int c = w * 4 + i;
    gA[i] = A + (size_t)(m0 + c * 8 + srow) * K + scol;
    gB[i] = Wm + (size_t)(n0 + c * 8 + srow) * K + scol;
  }

  f32x4 acc[4][4] = {};
  const int wr = w >> 1, wc = w & 1;
  const int fr = l & 15, fq = l >> 4;
  const int swz = (fr & 7) << 4;

  // prologue (FIFO): A(0) x4, B(0) x4, A(1) x4  -> 12 in flight
#pragma unroll
  for (int i = 0; i < 4; ++i) gload16(gA[i], &sA0[(w * 4 + i) * 512]);
#pragma unroll
  for (int i = 0; i < 4; ++i) gload16(gB[i], &sB0[(w * 4 + i) * 512]);
#pragma unroll
  for (int i = 0; i < 4; ++i)
    gload16(gA[i] + 64, &sA0[8192 + (w * 4 + i) * 512]);

  int cur = 0;
  for (int kt = 0; kt < NT; ++kt) {
    if (kt + 1 < NT)
      asm volatile("s_waitcnt vmcnt(4)" ::: "memory");
    else
      asm volatile("s_waitcnt vmcnt(0)" ::: "memory");
    __builtin_amdgcn_s_barrier();

    const char* ab = reinterpret_cast<const char*>(&sA0[cur * 8192]);
    const char* bb = reinterpret_cast<const char*>(sB0);
#pragma unroll
    for (int ks = 0; ks < 2; ++ks) {
      bf16x8 af[4], bfr[4];
#pragma unroll
      for (int mi = 0; mi < 4; ++mi)
        af[mi] = *reinterpret_cast<const bf16x8*>(
            ab + (wr * 64 + mi * 16 + fr) * 128 +
            ((ks * 64 + fq * 16) ^ swz));
#pragma unroll
      for (int ni = 0; ni < 4; ++ni)
        bfr[ni] = *reinterpret_cast<const bf16x8*>(
            bb + (wc * 64 + ni * 16 + fr) * 128 +
            ((ks * 64 + fq * 16) ^ swz));
#pragma unroll
      for (int mi = 0; mi < 4; ++mi)
#pragma unroll
        for (int ni = 0; ni < 4; ++ni)
          acc[mi][ni] = mfma16(af[mi], bfr[ni], acc[mi][ni]);
    }
    __builtin_amdgcn_s_barrier();  // all warps done reading sA[cur] + sB

    if (kt + 1 < NT) {
      const int ko = (kt + 1) * 64;
#pragma unroll
      for (int i = 0; i < 4; ++i)
        gload16(gB[i] + ko, &sB0[(w * 4 + i) * 512]);
    }
    if (kt + 2 < NT) {
      const int ko = (kt + 2) * 64;
#pragma unroll
      for (int i = 0; i < 4; ++i)
        gload16(gA[i] + ko, &sA0[cur * 8192 + (w * 4 + i) * 512]);
    }
    cur ^= 1;
  }

  // ---------------- epilogue ----------------
  if (MODE == 0 && mat == 2) {
#pragma unroll
    for (int mi = 0; mi < 4; ++mi) {
      const int mbase = m0 + wr * 64 + mi * 16 + fq * 4;
      const int b = mbase >> 11, s = mbase & (S_ - 1);
#pragma unroll
      for (int ni = 0; ni < 4; ++ni) {
        const int o = n0 + wc * 64 + ni * 16 + fr;
        const int h = o >> 6, hd = o & 63;
        bf16x4 vv;
#pragma unroll
        for (int r = 0; r < 4; ++r) vv[r] = (__bf16)acc[mi][ni][r];
        *reinterpret_cast<bf16x4*>(
            &Ov[((size_t)((b * H_ + h) * HD_ + hd)) * S_ + s]) = vv;
      }
    }
  } else {
    float* fW = reinterpret_cast<float*>(smem) + w * 2048;
#pragma unroll
    for (int half = 0; half < 2; ++half) {
#pragma unroll
      for (int mi2 = 0; mi2 < 2; ++mi2)
#pragma unroll
        for (int ni = 0; ni < 4; ++ni)
#pragma unroll
          for (int r = 0; r < 4; ++r)
            fW[(mi2 * 16 + fq * 4 + r) * 64 + ni * 16 + fr] =
                acc[half * 2 + mi2][ni][r];
      if (MODE == 1) {
        const int ocol = n0 + wc * 64 + fr * 4;
        const float4 bs = *reinterpret_cast<const float4*>(&bias[ocol]);
#pragma unroll
        for (int it = 0; it < 8; ++it) {
          const int lrow = it * 4 + fq;
          f32x4 v = *reinterpret_cast<const f32x4*>(&fW[lrow * 64 + fr * 4]);
          v[0] += bs.x;
          v[1] += bs.y;
          v[2] += bs.z;
          v[3] += bs.w;
          *reinterpret_cast<f32x4*>(
              &fout[(size_t)(m0 + wr * 64 + half * 32 + lrow) * D_ + ocol]) =
              v;
        }
      } else {
        const int o = n0 + wc * 64;  // 64-aligned -> h const
        const int h = o >> 6;
        __bf16* dst = (mat == 0) ? Oq : Ok;
#pragma unroll
        for (int it = 0; it < 8; ++it) {
          const int lrow = it * 4 + fq;
          const int m = m0 + wr * 64 + half * 32 + lrow;
          const int b = m >> 11, s = m & (S_ - 1);
          const f32x4 v =
              *reinterpret_cast<const f32x4*>(&fW[lrow * 64 + fr * 4]);
          bf16x4 ov;
#pragma unroll
          for (int r = 0; r < 4; ++r) ov[r] = (__bf16)v[r];
          *reinterpret_cast<bf16x4*>(
              &dst[((size_t)((b * H_ + h) * S_ + s)) * HD_ + fr * 4]) = ov;
        }
      }
    }
  }
}

// ---------------- causal flash attention: 64-q blocks, single-buffer V -------
// r27-exact (best measured, 111.9 us total): 4 warps x 16 q-rows, grid 1536,
// LDS 32 KB (sK dbuf + sV single + per-warp sP), counted vmcnt, vote-first
// defer-max (no cross-lane data movement on the common path), deferred
// l-reduction. r28's 8-warp variant regressed -> attn is pinned by its
// per-tile barrier-synced serial structure (~52 us across 7 variants).
__global__ __launch_bounds__(256)
__attribute__((amdgpu_waves_per_eu(5)))
void attn_kernel(const __bf16* __restrict__ Q, const __bf16* __restrict__ Kt,
                 const __bf16* __restrict__ Vt, __bf16* __restrict__ C) {
  __shared__ __align__(16) __bf16 sK[2][64 * 64];  // [kv][hd], swizzled, dbuf
  __shared__ __align__(16) __bf16 sV[64 * 64];     // V^T [hd][kv], single buf
  __shared__ __align__(16) __bf16 sP[4][16 * 64];  // per-warp P (2 KB)

  const int tid = threadIdx.x;
  const int l = tid & 63;
  const int w = tid >> 6;
  const int fr = l & 15, fq = l >> 4;
  const int bx = blockIdx.x;
  const int xcd = bx & 7;
  const int j = bx >> 3;             // [0, 192)
  const int bh = xcd + 8 * (j % 6);  // head in [0, 48), 6 per XCD
  const int qtile = 31 - j / 6;      // [0, 32), deep first
  const int qb = qtile * 64;
  const int qbw = qb + w * 16;  // this warp's 16 q-rows

  const __bf16* qh = Q + (size_t)bh * S_ * HD_;
  const __bf16* kh = Kt + (size_t)bh * S_ * HD_;
  const __bf16* vh = Vt + (size_t)bh * HD_ * S_;
  char* sPb = reinterpret_cast<char*>(&sP[w][0]);

  const int srow = l >> 3;                       // 0..7
  const int scol = ((l & 7) * 8) ^ (srow << 3);  // pre-swizzled source col
  const int swz = (fr & 7) << 4;                 // read-side XOR (bytes)

  bf16x8 qf[2];
#pragma unroll
  for (int ks = 0; ks < 2; ++ks)
    qf[ks] = *reinterpret_cast<const bf16x8*>(
        &qh[(size_t)(qbw + fr) * HD_ + ks * 32 + fq * 8]);

  f32x4 acc[4] = {};
  float mrow = -1e30f, lrow = 0.f;  // lrow: per-lane PARTIAL sum (deferred)

  const int nt = qtile + 1;  // kv tiles 0 .. qb/64
  int cur = 0;
  const int q0 = 2 * w, q1 = 2 * w + 1;

  gload16(kh + (size_t)(q0 * 8 + srow) * HD_ + scol, &sK[0][q0 * 512]);
  gload16(kh + (size_t)(q1 * 8 + srow) * HD_ + scol, &sK[0][q1 * 512]);
  gload16(vh + (size_t)(q0 * 8 + srow) * S_ + scol, &sV[q0 * 512]);
  gload16(vh + (size_t)(q1 * 8 + srow) * S_ + scol, &sV[q1 * 512]);
  if (nt > 1) {
    gload16(kh + (size_t)(64 + q0 * 8 + srow) * HD_ + scol, &sK[1][q0 * 512]);
    gload16(kh + (size_t)(64 + q1 * 8 + srow) * HD_ + scol, &sK[1][q1 * 512]);
  }

  for (int t = 0; t < nt; ++t) {
    if (t + 1 < nt)
      asm volatile("s_waitcnt vmcnt(2)" ::: "memory");
    else
      asm volatile("s_waitcnt vmcnt(0)" ::: "memory");
    __builtin_amdgcn_s_barrier();  // all warps' stage(t) landed

    const int kv0 = t * 64;
    if (kv0 <= qbw + 15) {
      const char* kb = reinterpret_cast<const char*>(&sK[cur][0]);
      const char* vb = reinterpret_cast<const char*>(&sV[0]);

      f32x4 s[4];
      __builtin_amdgcn_s_setprio(1);
#pragma unroll
      for (int c = 0; c < 4; ++c) {
        const int row = c * 16 + fr;
        bf16x8 kf0 = *reinterpret_cast<const bf16x8*>(
            kb + row * 128 + ((fq * 16) ^ swz));
        bf16x8 kf1 = *reinterpret_cast<const bf16x8*>(
            kb + row * 128 + ((fq * 16 + 64) ^ swz));
        f32x4 z = {};
        z = mfma16(kf0, qf[0], z);
        z = mfma16(kf1, qf[1], z);
        s[c] = z;
      }
      __builtin_amdgcn_s_setprio(0);

      if (kv0 + 63 > qbw) {
        const int qi = qbw + fr;
#pragma unroll
        for (int c = 0; c < 4; ++c)
#pragma unroll
          for (int r = 0; r < 4; ++r) {
            const int kvi = kv0 + c * 16 + fq * 4 + r;
            if (kvi > qi) s[c][r] = -1e30f;
          }
      }

      // lane-local max tree; vote-first defer (no shfl on common path)
      float tml = -1e30f;
#pragma unroll
      for (int c = 0; c < 4; ++c)
#pragma unroll
        for (int r = 0; r < 4; ++r) tml = fmaxf(tml, s[c][r]);
      const bool defer = __all(tml - mrow <= 8.0f);
      float mn;
      if (defer) {
        mn = mrow;
      } else {
        float tm = fmaxf(tml, __shfl_xor(tml, 16));
        tm = fmaxf(tm, __shfl_xor(tm, 32));
        mn = fmaxf(mrow, tm);
        const float fac = fexp2(mrow - mn);  // uniform across fq of a q-row
        mrow = mn;
        lrow *= fac;  // valid on per-lane partial sums
#pragma unroll
        for (int dt = 0; dt < 4; ++dt)
#pragma unroll
          for (int r = 0; r < 4; ++r) acc[dt][r] *= fac;
      }
      float sum = 0.f;
#pragma unroll
      for (int c = 0; c < 4; ++c) {
        bf16x4 pc;
#pragma unroll
        for (int r = 0; r < 4; ++r) {
          const float p = fexp2(s[c][r] - mn);
          sum += p;
          pc[r] = (__bf16)p;
        }
        const int bo = (c * 32 + fq * 8) ^ swz;
        *reinterpret_cast<bf16x4*>(sPb + fr * 128 + bo) = pc;
      }
      lrow += sum;  // cross-lane reduction deferred to epilogue

      bf16x8 pa[2];
#pragma unroll
      for (int ks = 0; ks < 2; ++ks) {
        const int bo = (ks * 64 + fq * 16) ^ swz;
        pa[ks] = *reinterpret_cast<const bf16x8*>(sPb + fr * 128 + bo);
      }

      __builtin_amdgcn_s_setprio(1);
#pragma unroll
      for (int dt = 0; dt < 4; ++dt) {
        const int row = dt * 16 + fr;
        bf16x8 vf0 = *reinterpret_cast<const bf16x8*>(
            vb + row * 128 + ((fq * 16) ^ swz));
        bf16x8 vf1 = *reinterpret_cast<const bf16x8*>(
            vb + row * 128 + ((fq * 16 + 64) ^ swz));
        acc[dt] = mfma16(vf0, pa[0], acc[dt]);
        acc[dt] = mfma16(vf1, pa[1], acc[dt]);
      }
      __builtin_amdgcn_s_setprio(0);
    }

    __builtin_amdgcn_s_barrier();  // all warps done reading sK[cur] + sV

    if (t + 1 < nt) {
      const int kvn = (t + 1) * 64;
      gload16(vh + (size_t)(q0 * 8 + srow) * S_ + kvn + scol, &sV[q0 * 512]);
      gload16(vh + (size_t)(q1 * 8 + srow) * S_ + kvn + scol, &sV[q1 * 512]);
    }
    if (t + 2 < nt) {
      const int kvn = (t + 2) * 64;
      gload16(kh + (size_t)(kvn + q0 * 8 + srow) * HD_ + scol,
              &sK[cur][q0 * 512]);
      gload16(kh + (size_t)(kvn + q1 * 8 + srow) * HD_ + scol,
              &sK[cur][q1 * 512]);
    }
    cur ^= 1;
  }

  float lt = lrow;
  lt += __shfl_xor(lt, 16);
  lt += __shfl_xor(lt, 32);
  const int b = bh / H_, h = bh % H_;
  const float inv_l = 1.0f / lt;
  const int qrow = qbw + fr;
#pragma unroll
  for (int dt = 0; dt < 4; ++dt) {
    bf16x4 ov;
#pragma unroll
    for (int r = 0; r < 4; ++r) ov[r] = (__bf16)(acc[dt][r] * inv_l);
    *reinterpret_cast<bf16x4*>(
        &C[((size_t)(b * S_ + qrow)) * D_ + h * HD_ + dt * 16 + fq * 4]) = ov;
  }
}

// ---------------- workspace layout (bf16 elements) ---------------------------
static constexpr size_t XB_OFF = 0;
static constexpr size_t WQ_OFF = XB_OFF + (size_t)T_ * D_;
static constexpr size_t WK_OFF = WQ_OFF + (size_t)D_ * D_;
static constexpr size_t WV_OFF = WK_OFF + (size_t)D_ * D_;
static constexpr size_t WO_OFF = WV_OFF + (size_t)D_ * D_;
static constexpr size_t Q_OFF = WO_OFF + (size_t)D_ * D_;
static constexpr size_t K_OFF = Q_OFF + (size_t)T_ * D_;
static constexpr size_t V_OFF = K_OFF + (size_t)T_ * D_;
static constexpr size_t C_OFF = V_OFF + (size_t)T_ * D_;

extern "C" void kernel_launch(void* const* d_in, const int* in_sizes, int n_in,
                              void* d_out, int out_size, void* d_ws,
                              size_t ws_size, hipStream_t stream) {
  const float* x = (const float*)d_in[0];
  const float* wq = (const float*)d_in[1];
  const float* wk = (const float*)d_in[2];
  const float* wv = (const float*)d_in[3];
  const float* wo = (const float*)d_in[4];
  const float* bo = (const float*)d_in[5];
  float* out = (float*)d_out;
  __bf16* ws = (__bf16*)d_ws;

  __bf16* xb = ws + XB_OFF;
  __bf16* wqb = ws + WQ_OFF;
  __bf16* wkb = ws + WK_OFF;
  __bf16* wvb = ws + WV_OFF;
  __bf16* wob = ws + WO_OFF;
  __bf16* qbuf = ws + Q_OFF;
  __bf16* kbuf = ws + K_OFF;
  __bf16* vbuf = ws + V_OFF;
  __bf16* cbuf = ws + C_OFF;

  {
    constexpr int n4 = T_ * D_ / 4 + 4 * (D_ * D_ / 4);
    cvt_all<<<(n4 + 255) / 256, 256, 0, stream>>>(x, wq, wk, wv, wo, ws);
  }

  gemm_bt<0><<<dim3(64, 18), 256, 0, stream>>>(
      xb, wqb, wkb, wvb, qbuf, kbuf, vbuf, nullptr, nullptr);

  attn_kernel<<<dim3(1536), 256, 0, stream>>>(qbuf, kbuf, vbuf, cbuf);

  gemm_bt<1><<<dim3(64, 6), 256, 0, stream>>>(
      cbuf, wob, nullptr, nullptr, nullptr, nullptr, nullptr, out, bo);
}